// Round 2
// baseline (9947.601 us; speedup 1.0000x reference)
//
#include <hip/hip_runtime.h>
#include <math.h>

#define T_STEPS 512
#define BATCH   16
#define DIM     1024
#define M_TOTAL (T_STEPS*BATCH)              // 8192
#define OUT_SEC ((size_t)M_TOTAL*DIM)        // 8388608 floats (output section)
#define BD      (BATCH*DIM)
#define NSLICE  16                           // D split into 16 slices of 64
#define CNT_STRIDE 16                        // ints per flag (64B padding)

// ---------------------------------------------------------------------------
// wave-wide sum reduction (64 lanes)
__device__ __forceinline__ float wred64(float v){
  #pragma unroll
  for (int off = 32; off >= 1; off >>= 1) v += __shfl_xor(v, off, 64);
  return v;
}

// ---------------------------------------------------------------------------
// Kernel A: entmax-1.5 gate. One wave per row of z [8192 rows x 1024].
// Writes gate into d_out's OUTPUT section (recurrence kernel consumes it,
// then overwrites with the final output).
__global__ __launch_bounds__(256) void gate_kernel(const float* __restrict__ z,
                                                   float* __restrict__ gate_out){
  const int row  = blockIdx.x * 4 + (threadIdx.x >> 6);
  const int lane = threadIdx.x & 63;
  const float* zr = z + (size_t)row * DIM;

  float x[16];
  #pragma unroll
  for (int e = 0; e < 4; ++e){
    float4 v = *reinterpret_cast<const float4*>(zr + e*256 + lane*4);
    x[e*4+0]=v.x; x[e*4+1]=v.y; x[e*4+2]=v.z; x[e*4+3]=v.w;
  }

  float m = x[0];
  #pragma unroll
  for (int i = 1; i < 16; ++i) m = fmaxf(m, x[i]);
  #pragma unroll
  for (int off = 32; off >= 1; off >>= 1) m = fmaxf(m, __shfl_xor(m, off, 64));

  // binary search for tau in [m-1, m]: f(tau)=sum relu(x-tau), f(lo)>=1>f(hi)
  float lo = m - 1.0f, hi = m;
  for (int it = 0; it < 30; ++it){
    float mid = 0.5f*(lo + hi);
    float f = 0.f;
    #pragma unroll
    for (int i = 0; i < 16; ++i) f += fmaxf(x[i] - mid, 0.f);
    f = wred64(f);
    if (f >= 1.0f) lo = mid; else hi = mid;
  }
  float s = 0.f, kc = 0.f;
  #pragma unroll
  for (int i = 0; i < 16; ++i){ if (x[i] > lo){ s += x[i]; kc += 1.f; } }
  s = wred64(s); kc = wred64(kc);
  const float tau = (s - 1.0f) / kc;

  float p[16]; float ps = 0.f;
  #pragma unroll
  for (int i = 0; i < 16; ++i){ p[i] = sqrtf(fmaxf(x[i] - tau, 0.f)); ps += p[i]; }
  ps = wred64(ps);
  const float inv = 1.0f / (ps + 1e-10f);

  float* go = gate_out + (size_t)row * DIM;
  #pragma unroll
  for (int e = 0; e < 4; ++e){
    float4 v; v.x=p[e*4]*inv; v.y=p[e*4+1]*inv; v.z=p[e*4+2]*inv; v.w=p[e*4+3]*inv;
    *reinterpret_cast<float4*>(go + e*256 + lane*4) = v;
  }
}

// ---------------------------------------------------------------------------
// Kernel B: pre[t,b,:] = x[t,b,:] @ Wx^T + bias  -> d_out H section, slot t+1
__global__ __launch_bounds__(256) void pre_gemm(const float* __restrict__ X,
                                                const float* __restrict__ Wx,
                                                const float* __restrict__ bias,
                                                float* __restrict__ out_h){
  __shared__ float a_s[64][17];
  __shared__ float w_s[64][17];
  const int tid = threadIdx.x;
  const int bm = blockIdx.x & 127, bn = blockIdx.x >> 7;
  const int m0 = bm*64, n0 = bn*64;
  const int lr = tid >> 2, lc = (tid & 3) * 4;
  const int tx = tid & 15, ty = tid >> 4;

  float acc[4][4] = {};

  for (int k0 = 0; k0 < DIM; k0 += 16){
    float4 av = *reinterpret_cast<const float4*>(X  + (size_t)(m0+lr)*DIM + k0 + lc);
    float4 wv = *reinterpret_cast<const float4*>(Wx + (size_t)(n0+lr)*DIM + k0 + lc);
    __syncthreads();
    a_s[lr][lc+0]=av.x; a_s[lr][lc+1]=av.y; a_s[lr][lc+2]=av.z; a_s[lr][lc+3]=av.w;
    w_s[lr][lc+0]=wv.x; w_s[lr][lc+1]=wv.y; w_s[lr][lc+2]=wv.z; w_s[lr][lc+3]=wv.w;
    __syncthreads();
    #pragma unroll
    for (int k = 0; k < 16; ++k){
      float af[4], wf[4];
      #pragma unroll
      for (int i = 0; i < 4; ++i) af[i] = a_s[ty*4+i][k];
      #pragma unroll
      for (int j = 0; j < 4; ++j) wf[j] = w_s[tx*4+j][k];
      #pragma unroll
      for (int i = 0; i < 4; ++i)
        #pragma unroll
        for (int j = 0; j < 4; ++j) acc[i][j] = fmaf(af[i], wf[j], acc[i][j]);
    }
  }

  const float4 bv = *reinterpret_cast<const float4*>(bias + n0 + tx*4);
  #pragma unroll
  for (int i = 0; i < 4; ++i){
    float4 v;
    v.x = acc[i][0]+bv.x; v.y = acc[i][1]+bv.y; v.z = acc[i][2]+bv.z; v.w = acc[i][3]+bv.w;
    *reinterpret_cast<float4*>(out_h + (size_t)(m0+ty*4+i+BATCH)*DIM + n0 + tx*4) = v;
  }
}

// ---------------------------------------------------------------------------
// Kernel C: persistent recurrence, batch-parallel sync groups.
// 256 blocks = 16 batches x 16 slices; 512 threads (8 waves).
// Block (b,s) owns outputs d in [s*64, s*64+64) for batch b; W_h slice is
// register-resident (128 VGPR/thread). Per step: read 4KB h[t][b] to regs,
// 128 FMA/thread, 64-lane shfl reduce, tanh, store, release per-(b,s) flag.
// Only the 16 blocks of the same batch synchronize with each other.
__global__ __launch_bounds__(512, 2) void rnn_kernel(const float* __restrict__ h0,
                                                     const float* __restrict__ Wh,
                                                     float* __restrict__ out,
                                                     unsigned* __restrict__ prog){
  float* out_h = out + OUT_SEC;
  const int tid  = threadIdx.x;
  const int lane = tid & 63;
  const int w    = tid >> 6;            // wave 0..7
  const int b    = blockIdx.x >> 4;     // batch 0..15
  const int s    = blockIdx.x & 15;     // slice 0..15
  const int dbase = s*64 + w*8;         // this wave's 8 output rows

  // register-resident W_h slice: 8 rows x 16 cols (as 4x float4 per row)
  float4 wreg[8][4];
  #pragma unroll
  for (int r = 0; r < 8; ++r)
    #pragma unroll
    for (int j = 0; j < 4; ++j)
      wreg[r][j] = *reinterpret_cast<const float4*>(
          Wh + (size_t)(dbase + r)*DIM + lane*4 + j*256);

  // h[0] = h0 (output slot 0); block copies its 64-float slice
  if (tid < 16)
    reinterpret_cast<float4*>(out_h + (size_t)b*DIM + s*64)[tid] =
        reinterpret_cast<const float4*>(h0 + (size_t)b*DIM + s*64)[tid];

  for (int t = 0; t < T_STEPS; ++t){
    // prefetch pre (h slot t+1) and gate (out slot t) for own region
    float pre_v = 0.f, gate_v = 0.f;
    if (lane < 8){
      const size_t d = dbase + lane;
      pre_v  = out_h[(size_t)(t+1)*BD + (size_t)b*DIM + d];
      gate_v = out  [(size_t)t*BD     + (size_t)b*DIM + d];
    }

    // wait for all 16 slices of h[t][b] (skip at t=0: read h0 directly)
    if (t > 0){
      if (tid < NSLICE){
        while (__hip_atomic_load(&prog[(b*NSLICE + tid)*CNT_STRIDE],
                                 __ATOMIC_ACQUIRE, __HIP_MEMORY_SCOPE_AGENT) < (unsigned)t)
          __builtin_amdgcn_s_sleep(2);
      }
      __syncthreads();
    }

    // load h[t][b] (4KB) into registers, coalesced
    const float* hsrc = (t == 0) ? (h0 + (size_t)b*DIM)
                                 : (out_h + (size_t)t*BD + (size_t)b*DIM);
    float4 hv[4];
    #pragma unroll
    for (int j = 0; j < 4; ++j)
      hv[j] = *reinterpret_cast<const float4*>(hsrc + lane*4 + j*256);

    // 8 rows x 16 FMA, then 64-lane butterfly reduce per row
    #pragma unroll
    for (int r = 0; r < 8; ++r){
      float a = 0.f;
      #pragma unroll
      for (int j = 0; j < 4; ++j){
        const float4 ww = wreg[r][j], hh = hv[j];
        a = fmaf(ww.x, hh.x, fmaf(ww.y, hh.y, fmaf(ww.z, hh.z, fmaf(ww.w, hh.w, a))));
      }
      a += __shfl_xor(a, 1, 64);
      a += __shfl_xor(a, 2, 64);
      a += __shfl_xor(a, 4, 64);
      a += __shfl_xor(a, 8, 64);
      a += __shfl_xor(a, 16, 64);
      a += __shfl_xor(a, 32, 64);
      if (lane == r){
        const float hn = tanhf(pre_v + a);
        const size_t d = dbase + lane;
        out_h[(size_t)(t+1)*BD + (size_t)b*DIM + d] = hn;   // h[t+1] (over pre)
        out  [(size_t)t*BD     + (size_t)b*DIM + d] = hn * gate_v; // out[t] (over gate)
      }
    }

    __syncthreads();
    if (tid == 0){
      __threadfence();
      __hip_atomic_store(&prog[(b*NSLICE + s)*CNT_STRIDE], (unsigned)(t+1),
                         __ATOMIC_RELEASE, __HIP_MEMORY_SCOPE_AGENT);
    }
  }
}

// ---------------------------------------------------------------------------
extern "C" void kernel_launch(void* const* d_in, const int* in_sizes, int n_in,
                              void* d_out, int out_size, void* d_ws, size_t ws_size,
                              hipStream_t stream){
  (void)in_sizes; (void)n_in; (void)out_size; (void)ws_size;
  const float* x    = (const float*)d_in[0];
  const float* z    = (const float*)d_in[1];
  const float* h0   = (const float*)d_in[2];
  const float* Wx   = (const float*)d_in[3];
  const float* Wh   = (const float*)d_in[4];
  const float* bias = (const float*)d_in[5];
  float* out   = (float*)d_out;
  float* out_h = out + OUT_SEC;
  unsigned* prog = (unsigned*)d_ws;

  // 16 batches x 16 slices flags, 64B apart
  hipMemsetAsync(d_ws, 0, BATCH*NSLICE*CNT_STRIDE*sizeof(unsigned), stream);
  gate_kernel<<<2048, 256, 0, stream>>>(z, out);              // gate -> output section
  pre_gemm   <<<2048, 256, 0, stream>>>(x, Wx, bias, out_h);  // pre  -> h section (t+1)
  rnn_kernel <<<256, 512, 0, stream>>>(h0, Wh, out, prog);
}

// Round 3
// 5360.962 us; speedup vs baseline: 1.8556x; 1.8556x over previous
//
#include <hip/hip_runtime.h>
#include <math.h>

#define T_STEPS 512
#define BATCH   16
#define DIM     1024
#define M_TOTAL (T_STEPS*BATCH)              // 8192
#define OUT_SEC ((size_t)M_TOTAL*DIM)        // 8388608 floats (output section)
#define BD      (BATCH*DIM)
#define NSLICE  16                           // D split into 16 slices of 64
#define CNT_STRIDE 32                        // ints per counter (128B padding)

// ---------------------------------------------------------------------------
// wave-wide sum reduction (64 lanes)
__device__ __forceinline__ float wred64(float v){
  #pragma unroll
  for (int off = 32; off >= 1; off >>= 1) v += __shfl_xor(v, off, 64);
  return v;
}

// ---------------------------------------------------------------------------
// Kernel A: entmax-1.5 gate. One wave per row of z [8192 rows x 1024].
// Writes gate into d_out's OUTPUT section (recurrence kernel consumes it,
// then overwrites with the final output).
__global__ __launch_bounds__(256) void gate_kernel(const float* __restrict__ z,
                                                   float* __restrict__ gate_out){
  const int row  = blockIdx.x * 4 + (threadIdx.x >> 6);
  const int lane = threadIdx.x & 63;
  const float* zr = z + (size_t)row * DIM;

  float x[16];
  #pragma unroll
  for (int e = 0; e < 4; ++e){
    float4 v = *reinterpret_cast<const float4*>(zr + e*256 + lane*4);
    x[e*4+0]=v.x; x[e*4+1]=v.y; x[e*4+2]=v.z; x[e*4+3]=v.w;
  }

  float m = x[0];
  #pragma unroll
  for (int i = 1; i < 16; ++i) m = fmaxf(m, x[i]);
  #pragma unroll
  for (int off = 32; off >= 1; off >>= 1) m = fmaxf(m, __shfl_xor(m, off, 64));

  // binary search for tau in [m-1, m]: f(tau)=sum relu(x-tau), f(lo)>=1>f(hi)
  float lo = m - 1.0f, hi = m;
  for (int it = 0; it < 30; ++it){
    float mid = 0.5f*(lo + hi);
    float f = 0.f;
    #pragma unroll
    for (int i = 0; i < 16; ++i) f += fmaxf(x[i] - mid, 0.f);
    f = wred64(f);
    if (f >= 1.0f) lo = mid; else hi = mid;
  }
  float s = 0.f, kc = 0.f;
  #pragma unroll
  for (int i = 0; i < 16; ++i){ if (x[i] > lo){ s += x[i]; kc += 1.f; } }
  s = wred64(s); kc = wred64(kc);
  const float tau = (s - 1.0f) / kc;

  float p[16]; float ps = 0.f;
  #pragma unroll
  for (int i = 0; i < 16; ++i){ p[i] = sqrtf(fmaxf(x[i] - tau, 0.f)); ps += p[i]; }
  ps = wred64(ps);
  const float inv = 1.0f / (ps + 1e-10f);

  float* go = gate_out + (size_t)row * DIM;
  #pragma unroll
  for (int e = 0; e < 4; ++e){
    float4 v; v.x=p[e*4]*inv; v.y=p[e*4+1]*inv; v.z=p[e*4+2]*inv; v.w=p[e*4+3]*inv;
    *reinterpret_cast<float4*>(go + e*256 + lane*4) = v;
  }
}

// ---------------------------------------------------------------------------
// Kernel B: pre[t,b,:] = x[t,b,:] @ Wx^T + bias  -> d_out H section, slot t+1
__global__ __launch_bounds__(256) void pre_gemm(const float* __restrict__ X,
                                                const float* __restrict__ Wx,
                                                const float* __restrict__ bias,
                                                float* __restrict__ out_h){
  __shared__ float a_s[64][17];
  __shared__ float w_s[64][17];
  const int tid = threadIdx.x;
  const int bm = blockIdx.x & 127, bn = blockIdx.x >> 7;
  const int m0 = bm*64, n0 = bn*64;
  const int lr = tid >> 2, lc = (tid & 3) * 4;
  const int tx = tid & 15, ty = tid >> 4;

  float acc[4][4] = {};

  for (int k0 = 0; k0 < DIM; k0 += 16){
    float4 av = *reinterpret_cast<const float4*>(X  + (size_t)(m0+lr)*DIM + k0 + lc);
    float4 wv = *reinterpret_cast<const float4*>(Wx + (size_t)(n0+lr)*DIM + k0 + lc);
    __syncthreads();
    a_s[lr][lc+0]=av.x; a_s[lr][lc+1]=av.y; a_s[lr][lc+2]=av.z; a_s[lr][lc+3]=av.w;
    w_s[lr][lc+0]=wv.x; w_s[lr][lc+1]=wv.y; w_s[lr][lc+2]=wv.z; w_s[lr][lc+3]=wv.w;
    __syncthreads();
    #pragma unroll
    for (int k = 0; k < 16; ++k){
      float af[4], wf[4];
      #pragma unroll
      for (int i = 0; i < 4; ++i) af[i] = a_s[ty*4+i][k];
      #pragma unroll
      for (int j = 0; j < 4; ++j) wf[j] = w_s[tx*4+j][k];
      #pragma unroll
      for (int i = 0; i < 4; ++i)
        #pragma unroll
        for (int j = 0; j < 4; ++j) acc[i][j] = fmaf(af[i], wf[j], acc[i][j]);
    }
  }

  const float4 bv = *reinterpret_cast<const float4*>(bias + n0 + tx*4);
  #pragma unroll
  for (int i = 0; i < 4; ++i){
    float4 v;
    v.x = acc[i][0]+bv.x; v.y = acc[i][1]+bv.y; v.z = acc[i][2]+bv.z; v.w = acc[i][3]+bv.w;
    *reinterpret_cast<float4*>(out_h + (size_t)(m0+ty*4+i+BATCH)*DIM + n0 + tx*4) = v;
  }
}

// ---------------------------------------------------------------------------
// Kernel C: persistent recurrence, batch-parallel sync groups, LLC-mediated.
// 256 blocks = 16 batches x 16 slices; 512 threads (8 waves), 1 block/CU.
// All cross-block comm (h, counter) via relaxed agent atomics = sc0 sc1
// (bypass L1/L2, serialize at LLC). NO acquire fences, NO buffer_inv in loop.
#define KA(v) asm volatile("" : "+v"(v.x), "+v"(v.y), "+v"(v.z), "+v"(v.w))

__global__ __launch_bounds__(512) void rnn_kernel(const float* __restrict__ h0,
                                                  const float* __restrict__ Wh,
                                                  float* __restrict__ out,
                                                  unsigned* __restrict__ prog){
  float* out_h = out + OUT_SEC;
  const int tid  = threadIdx.x;
  const int lane = tid & 63;
  const int w    = tid >> 6;            // wave 0..7
  const int b    = blockIdx.x >> 4;     // batch 0..15
  const int s    = blockIdx.x & 15;     // slice 0..15
  const int dbase = s*64 + w*8;         // this wave's 8 output rows

  // register-resident W_h slice: 8 rows x 16 cols (4x float4 per row)
  float4 wreg[8][4];
  #pragma unroll
  for (int r = 0; r < 8; ++r)
    #pragma unroll
    for (int j = 0; j < 4; ++j)
      wreg[r][j] = *reinterpret_cast<const float4*>(
          Wh + (size_t)(dbase + r)*DIM + lane*4 + j*256);

  // h[0] = h0 (output slot 0, validation only); block copies its 64-float slice
  if (tid < 16)
    reinterpret_cast<float4*>(out_h + (size_t)b*DIM + s*64)[tid] =
        reinterpret_cast<const float4*>(h0 + (size_t)b*DIM + s*64)[tid];

  unsigned* cnt = &prog[b * CNT_STRIDE];

  for (int t = 0; t < T_STEPS; ++t){
    // keep-alive: force the 128 weight VGPRs to stay resident across the loop
    KA(wreg[0][0]); KA(wreg[0][1]); KA(wreg[0][2]); KA(wreg[0][3]);
    KA(wreg[1][0]); KA(wreg[1][1]); KA(wreg[1][2]); KA(wreg[1][3]);
    KA(wreg[2][0]); KA(wreg[2][1]); KA(wreg[2][2]); KA(wreg[2][3]);
    KA(wreg[3][0]); KA(wreg[3][1]); KA(wreg[3][2]); KA(wreg[3][3]);
    KA(wreg[4][0]); KA(wreg[4][1]); KA(wreg[4][2]); KA(wreg[4][3]);
    KA(wreg[5][0]); KA(wreg[5][1]); KA(wreg[5][2]); KA(wreg[5][3]);
    KA(wreg[6][0]); KA(wreg[6][1]); KA(wreg[6][2]); KA(wreg[6][3]);
    KA(wreg[7][0]); KA(wreg[7][1]); KA(wreg[7][2]); KA(wreg[7][3]);

    // prefetch pre (h slot t+1) and gate (out slot t) for own region (cached:
    // written before this kernel launched, never modified by other blocks)
    float pre_v = 0.f, gate_v = 0.f;
    if (lane < 8){
      const size_t d = dbase + lane;
      pre_v  = out_h[(size_t)(t+1)*BD + (size_t)b*DIM + d];
      gate_v = out  [(size_t)t*BD     + (size_t)b*DIM + d];
    }

    // wait for all 16 slices of h[t][b] (skip at t=0: read h0 directly).
    // RELAXED spin: no cache invalidation per poll.
    if (t > 0){
      if (tid == 0){
        while (__hip_atomic_load(cnt, __ATOMIC_RELAXED, __HIP_MEMORY_SCOPE_AGENT)
               < (unsigned)(NSLICE * t))
          __builtin_amdgcn_s_sleep(1);
      }
      __syncthreads();
    }

    // load h[t][b] (4KB) via LLC-bypass dword loads (L1/L2 may hold stale
    // pre-values at these addresses from the prefetch above)
    const float* hsrc = (t == 0) ? (h0 + (size_t)b*DIM)
                                 : (out_h + (size_t)t*BD + (size_t)b*DIM);
    float hx[16];
    #pragma unroll
    for (int j = 0; j < 4; ++j)
      #pragma unroll
      for (int c = 0; c < 4; ++c)
        hx[j*4+c] = __hip_atomic_load(hsrc + lane*4 + j*256 + c,
                                      __ATOMIC_RELAXED, __HIP_MEMORY_SCOPE_AGENT);

    // 8 rows x 16 FMA, then 64-lane butterfly reduce per row
    #pragma unroll
    for (int r = 0; r < 8; ++r){
      float a = 0.f;
      #pragma unroll
      for (int j = 0; j < 4; ++j){
        const float4 ww = wreg[r][j];
        a = fmaf(ww.x, hx[j*4+0], fmaf(ww.y, hx[j*4+1],
            fmaf(ww.z, hx[j*4+2], fmaf(ww.w, hx[j*4+3], a))));
      }
      a += __shfl_xor(a, 1, 64);
      a += __shfl_xor(a, 2, 64);
      a += __shfl_xor(a, 4, 64);
      a += __shfl_xor(a, 8, 64);
      a += __shfl_xor(a, 16, 64);
      a += __shfl_xor(a, 32, 64);
      if (lane == r){
        const float hn = tanhf(pre_v + a);
        const size_t d = dbase + lane;
        // h[t+1]: LLC-direct store (readers bypass caches)
        __hip_atomic_store(out_h + (size_t)(t+1)*BD + (size_t)b*DIM + d, hn,
                           __ATOMIC_RELAXED, __HIP_MEMORY_SCOPE_AGENT);
        // output[t]: plain cached store (read only by validation after kernel)
        out[(size_t)t*BD + (size_t)b*DIM + d] = hn * gate_v;
      }
    }

    __syncthreads();
    if (tid == 0){
      // RELEASE orders this block's h stores (already at LLC, vmcnt-drained
      // by the fence) before the counter bump.
      __hip_atomic_fetch_add(cnt, 1u, __ATOMIC_RELEASE, __HIP_MEMORY_SCOPE_AGENT);
    }
  }
}

// ---------------------------------------------------------------------------
extern "C" void kernel_launch(void* const* d_in, const int* in_sizes, int n_in,
                              void* d_out, int out_size, void* d_ws, size_t ws_size,
                              hipStream_t stream){
  (void)in_sizes; (void)n_in; (void)out_size; (void)ws_size;
  const float* x    = (const float*)d_in[0];
  const float* z    = (const float*)d_in[1];
  const float* h0   = (const float*)d_in[2];
  const float* Wx   = (const float*)d_in[3];
  const float* Wh   = (const float*)d_in[4];
  const float* bias = (const float*)d_in[5];
  float* out   = (float*)d_out;
  float* out_h = out + OUT_SEC;
  unsigned* prog = (unsigned*)d_ws;

  hipMemsetAsync(d_ws, 0, BATCH*CNT_STRIDE*sizeof(unsigned), stream);
  gate_kernel<<<2048, 256, 0, stream>>>(z, out);              // gate -> output section
  pre_gemm   <<<2048, 256, 0, stream>>>(x, Wx, bias, out_h);  // pre  -> h section (t+1)
  rnn_kernel <<<256, 512, 0, stream>>>(h0, Wh, out, prog);
}

// Round 4
// 1864.920 us; speedup vs baseline: 5.3341x; 2.8746x over previous
//
#include <hip/hip_runtime.h>
#include <math.h>

#define T_STEPS 512
#define BATCH   16
#define DIM     1024
#define M_TOTAL (T_STEPS*BATCH)              // 8192
#define OUT_SEC ((size_t)M_TOTAL*DIM)        // 8388608 floats (output section)
#define BD      (BATCH*DIM)
#define NSLICE  16                           // D split into 16 slices of 64
#define CNT_STRIDE 32                        // ints per counter (128B padding)

// ---------------------------------------------------------------------------
// wave-wide sum reduction (64 lanes)
__device__ __forceinline__ float wred64(float v){
  #pragma unroll
  for (int off = 32; off >= 1; off >>= 1) v += __shfl_xor(v, off, 64);
  return v;
}

// ---------------------------------------------------------------------------
// Kernel A: entmax-1.5 gate. One wave per row of z [8192 rows x 1024].
__global__ __launch_bounds__(256) void gate_kernel(const float* __restrict__ z,
                                                   float* __restrict__ gate_out){
  const int row  = blockIdx.x * 4 + (threadIdx.x >> 6);
  const int lane = threadIdx.x & 63;
  const float* zr = z + (size_t)row * DIM;

  float x[16];
  #pragma unroll
  for (int e = 0; e < 4; ++e){
    float4 v = *reinterpret_cast<const float4*>(zr + e*256 + lane*4);
    x[e*4+0]=v.x; x[e*4+1]=v.y; x[e*4+2]=v.z; x[e*4+3]=v.w;
  }

  float m = x[0];
  #pragma unroll
  for (int i = 1; i < 16; ++i) m = fmaxf(m, x[i]);
  #pragma unroll
  for (int off = 32; off >= 1; off >>= 1) m = fmaxf(m, __shfl_xor(m, off, 64));

  // binary search for tau in [m-1, m]: f(tau)=sum relu(x-tau), f(lo)>=1>f(hi)
  float lo = m - 1.0f, hi = m;
  for (int it = 0; it < 30; ++it){
    float mid = 0.5f*(lo + hi);
    float f = 0.f;
    #pragma unroll
    for (int i = 0; i < 16; ++i) f += fmaxf(x[i] - mid, 0.f);
    f = wred64(f);
    if (f >= 1.0f) lo = mid; else hi = mid;
  }
  float s = 0.f, kc = 0.f;
  #pragma unroll
  for (int i = 0; i < 16; ++i){ if (x[i] > lo){ s += x[i]; kc += 1.f; } }
  s = wred64(s); kc = wred64(kc);
  const float tau = (s - 1.0f) / kc;

  float p[16]; float ps = 0.f;
  #pragma unroll
  for (int i = 0; i < 16; ++i){ p[i] = sqrtf(fmaxf(x[i] - tau, 0.f)); ps += p[i]; }
  ps = wred64(ps);
  const float inv = 1.0f / (ps + 1e-10f);

  float* go = gate_out + (size_t)row * DIM;
  #pragma unroll
  for (int e = 0; e < 4; ++e){
    float4 v; v.x=p[e*4]*inv; v.y=p[e*4+1]*inv; v.z=p[e*4+2]*inv; v.w=p[e*4+3]*inv;
    *reinterpret_cast<float4*>(go + e*256 + lane*4) = v;
  }
}

// ---------------------------------------------------------------------------
// Kernel B: pre[t,b,:] = x[t,b,:] @ Wx^T + bias  -> d_out H section, slot t+1
__global__ __launch_bounds__(256) void pre_gemm(const float* __restrict__ X,
                                                const float* __restrict__ Wx,
                                                const float* __restrict__ bias,
                                                float* __restrict__ out_h){
  __shared__ float a_s[64][17];
  __shared__ float w_s[64][17];
  const int tid = threadIdx.x;
  const int bm = blockIdx.x & 127, bn = blockIdx.x >> 7;
  const int m0 = bm*64, n0 = bn*64;
  const int lr = tid >> 2, lc = (tid & 3) * 4;
  const int tx = tid & 15, ty = tid >> 4;

  float acc[4][4] = {};

  for (int k0 = 0; k0 < DIM; k0 += 16){
    float4 av = *reinterpret_cast<const float4*>(X  + (size_t)(m0+lr)*DIM + k0 + lc);
    float4 wv = *reinterpret_cast<const float4*>(Wx + (size_t)(n0+lr)*DIM + k0 + lc);
    __syncthreads();
    a_s[lr][lc+0]=av.x; a_s[lr][lc+1]=av.y; a_s[lr][lc+2]=av.z; a_s[lr][lc+3]=av.w;
    w_s[lr][lc+0]=wv.x; w_s[lr][lc+1]=wv.y; w_s[lr][lc+2]=wv.z; w_s[lr][lc+3]=wv.w;
    __syncthreads();
    #pragma unroll
    for (int k = 0; k < 16; ++k){
      float af[4], wf[4];
      #pragma unroll
      for (int i = 0; i < 4; ++i) af[i] = a_s[ty*4+i][k];
      #pragma unroll
      for (int j = 0; j < 4; ++j) wf[j] = w_s[tx*4+j][k];
      #pragma unroll
      for (int i = 0; i < 4; ++i)
        #pragma unroll
        for (int j = 0; j < 4; ++j) acc[i][j] = fmaf(af[i], wf[j], acc[i][j]);
    }
  }

  const float4 bv = *reinterpret_cast<const float4*>(bias + n0 + tx*4);
  #pragma unroll
  for (int i = 0; i < 4; ++i){
    float4 v;
    v.x = acc[i][0]+bv.x; v.y = acc[i][1]+bv.y; v.z = acc[i][2]+bv.z; v.w = acc[i][3]+bv.w;
    *reinterpret_cast<float4*>(out_h + (size_t)(m0+ty*4+i+BATCH)*DIM + n0 + tx*4) = v;
  }
}

// ---------------------------------------------------------------------------
// Kernel C: persistent recurrence, batch-parallel sync groups, LLC-mediated.
// 256 blocks = 16 batches x 16 slices; 512 threads (8 waves), 1 block/CU.
// Cross-block protocol: h stores + counter all L1/L2-bypass (LLC-serialized).
// NO release fences in the loop (no buffer_wbl2), ordering via vmcnt drain.
#define KA(v) asm volatile("" : "+v"(v.x), "+v"(v.y), "+v"(v.z), "+v"(v.w))

__global__ __launch_bounds__(512, 1) void rnn_kernel(const float* __restrict__ h0,
                                                     const float* __restrict__ Wh,
                                                     float* __restrict__ out,
                                                     unsigned* __restrict__ prog){
  float* out_h = out + OUT_SEC;
  const int tid  = threadIdx.x;
  const int lane = tid & 63;
  const int w    = tid >> 6;            // wave 0..7
  const int b    = blockIdx.x >> 4;     // batch 0..15
  const int s    = blockIdx.x & 15;     // slice 0..15
  const int dbase = s*64 + w*8;         // this wave's 8 output rows

  // register-resident W_h slice: 8 rows x 16 cols (4x float4 per row)
  float4 wreg[8][4];
  #pragma unroll
  for (int r = 0; r < 8; ++r)
    #pragma unroll
    for (int j = 0; j < 4; ++j)
      wreg[r][j] = *reinterpret_cast<const float4*>(
          Wh + (size_t)(dbase + r)*DIM + lane*4 + j*256);

  // One-time keep-alive: values become asm-defined -> cannot be
  // rematerialized from memory inside the loop; must stay live.
  KA(wreg[0][0]); KA(wreg[0][1]); KA(wreg[0][2]); KA(wreg[0][3]);
  KA(wreg[1][0]); KA(wreg[1][1]); KA(wreg[1][2]); KA(wreg[1][3]);
  KA(wreg[2][0]); KA(wreg[2][1]); KA(wreg[2][2]); KA(wreg[2][3]);
  KA(wreg[3][0]); KA(wreg[3][1]); KA(wreg[3][2]); KA(wreg[3][3]);
  KA(wreg[4][0]); KA(wreg[4][1]); KA(wreg[4][2]); KA(wreg[4][3]);
  KA(wreg[5][0]); KA(wreg[5][1]); KA(wreg[5][2]); KA(wreg[5][3]);
  KA(wreg[6][0]); KA(wreg[6][1]); KA(wreg[6][2]); KA(wreg[6][3]);
  KA(wreg[7][0]); KA(wreg[7][1]); KA(wreg[7][2]); KA(wreg[7][3]);

  // h[0] = h0 (output slot 0, validation only); block copies its 64-float slice
  if (tid < 16)
    reinterpret_cast<float4*>(out_h + (size_t)b*DIM + s*64)[tid] =
        reinterpret_cast<const float4*>(h0 + (size_t)b*DIM + s*64)[tid];

  unsigned* cnt = &prog[b * CNT_STRIDE];

  for (int t = 0; t < T_STEPS; ++t){
    // prefetch pre (h slot t+1) and gate (out slot t) for own region (cached;
    // only this block ever touches these addresses before they're consumed)
    float pre_v = 0.f, gate_v = 0.f;
    if (lane < 8){
      const size_t d = dbase + lane;
      pre_v  = out_h[(size_t)(t+1)*BD + (size_t)b*DIM + d];
      gate_v = out  [(size_t)t*BD     + (size_t)b*DIM + d];
    }

    // wait for all 16 slices of h[t][b] (skip at t=0: read h0 directly).
    // RELAXED spin: no cache maintenance per poll.
    if (t > 0){
      if (tid == 0){
        while (__hip_atomic_load(cnt, __ATOMIC_RELAXED, __HIP_MEMORY_SCOPE_AGENT)
               < (unsigned)(NSLICE * t)) { }
      }
      __syncthreads();
    }

    // load h[t][b] (4KB) with L1/L2-bypass dwordx4; waitcnt INSIDE the asm so
    // nothing dependent can be scheduled between load and wait.
    const float* hsrc = (t == 0) ? (h0 + (size_t)b*DIM)
                                 : (out_h + (size_t)t*BD + (size_t)b*DIM);
    const float* a0 = hsrc + lane*4;
    const float* a1 = a0 + 256;
    const float* a2 = a0 + 512;
    const float* a3 = a0 + 768;
    float4 hv0, hv1, hv2, hv3;
    asm volatile(
      "global_load_dwordx4 %0, %4, off sc0 sc1\n\t"
      "global_load_dwordx4 %1, %5, off sc0 sc1\n\t"
      "global_load_dwordx4 %2, %6, off sc0 sc1\n\t"
      "global_load_dwordx4 %3, %7, off sc0 sc1\n\t"
      "s_waitcnt vmcnt(0)"
      : "=&v"(hv0), "=&v"(hv1), "=&v"(hv2), "=&v"(hv3)
      : "v"(a0), "v"(a1), "v"(a2), "v"(a3)
      : "memory");

    // 8 rows x 16 FMA; butterfly-reduce; capture row r's result in lane r
    float myv = 0.f;
    #pragma unroll
    for (int r = 0; r < 8; ++r){
      float a = 0.f;
      {
        const float4 w0 = wreg[r][0], w1 = wreg[r][1],
                     w2 = wreg[r][2], w3 = wreg[r][3];
        a = fmaf(w0.x, hv0.x, fmaf(w0.y, hv0.y, fmaf(w0.z, hv0.z, fmaf(w0.w, hv0.w, a))));
        a = fmaf(w1.x, hv1.x, fmaf(w1.y, hv1.y, fmaf(w1.z, hv1.z, fmaf(w1.w, hv1.w, a))));
        a = fmaf(w2.x, hv2.x, fmaf(w2.y, hv2.y, fmaf(w2.z, hv2.z, fmaf(w2.w, hv2.w, a))));
        a = fmaf(w3.x, hv3.x, fmaf(w3.y, hv3.y, fmaf(w3.z, hv3.z, fmaf(w3.w, hv3.w, a))));
      }
      a += __shfl_xor(a, 1, 64);
      a += __shfl_xor(a, 2, 64);
      a += __shfl_xor(a, 4, 64);
      a += __shfl_xor(a, 8, 64);
      a += __shfl_xor(a, 16, 64);
      a += __shfl_xor(a, 32, 64);
      if (lane == r) myv = a;          // v_cndmask, no divergence
    }

    // single epilogue: one fast tanh + two stores for lanes 0..7
    if (lane < 8){
      const float v  = pre_v + myv;
      const float e  = __expf(2.0f * v);
      const float hn = 1.0f - 2.0f / (e + 1.0f);   // tanh(v); inf-safe
      const size_t d = dbase + lane;
      // h[t+1]: LLC-direct store (readers bypass caches)
      __hip_atomic_store(out_h + (size_t)(t+1)*BD + (size_t)b*DIM + d, hn,
                         __ATOMIC_RELAXED, __HIP_MEMORY_SCOPE_AGENT);
      // output[t]: plain cached store (read only after kernel end)
      out[(size_t)t*BD + (size_t)b*DIM + d] = hn * gate_v;
    }

    __syncthreads();
    if (tid == 0){
      // Drain our bypass stores to the LLC, then publish with a RELAXED add
      // (no buffer_wbl2 — nothing release-fenced in the loop).
      asm volatile("s_waitcnt vmcnt(0)" ::: "memory");
      __hip_atomic_fetch_add(cnt, 1u, __ATOMIC_RELAXED, __HIP_MEMORY_SCOPE_AGENT);
    }
  }
}

// ---------------------------------------------------------------------------
extern "C" void kernel_launch(void* const* d_in, const int* in_sizes, int n_in,
                              void* d_out, int out_size, void* d_ws, size_t ws_size,
                              hipStream_t stream){
  (void)in_sizes; (void)n_in; (void)out_size; (void)ws_size;
  const float* x    = (const float*)d_in[0];
  const float* z    = (const float*)d_in[1];
  const float* h0   = (const float*)d_in[2];
  const float* Wx   = (const float*)d_in[3];
  const float* Wh   = (const float*)d_in[4];
  const float* bias = (const float*)d_in[5];
  float* out   = (float*)d_out;
  float* out_h = out + OUT_SEC;
  unsigned* prog = (unsigned*)d_ws;

  hipMemsetAsync(d_ws, 0, BATCH*CNT_STRIDE*sizeof(unsigned), stream);
  gate_kernel<<<2048, 256, 0, stream>>>(z, out);              // gate -> output section
  pre_gemm   <<<2048, 256, 0, stream>>>(x, Wx, bias, out_h);  // pre  -> h section (t+1)
  rnn_kernel <<<256, 512, 0, stream>>>(h0, Wh, out, prog);
}